// Round 10
// baseline (496.621 us; speedup 1.0000x reference)
//
#include <hip/hip_runtime.h>
#include <hip/hip_bf16.h>

// Problem constants (match reference)
static constexpr int NN  = 100000;   // nodes
static constexpr int NE  = 1600000;  // edges
static constexpr int DIM = 128;
static constexpr int OC  = 10;
static constexpr int BK  = 64;       // bucket capacity (max deg ~45 for Poisson(16))
static constexpr float BN_EPS = 1e-5f;
static constexpr float INVN   = 1.0f / (float)NN;

// edge binning: bin = dst>>9 (512 nodes/bin); per-bin buffer capacity
static constexpr int BINS = 196;     // ceil(100000/512)
static constexpr int CAP  = 16320;   // slots/bin (mult of 8); 196*16320*8B = 25.59MB fits B_bf
static constexpr int EPB  = 2048;    // edges per binning block
static constexpr int P1B  = (NE + EPB - 1) / EPB;   // 782 binning blocks

typedef unsigned short ushortT;
typedef unsigned int uintT;
typedef __attribute__((ext_vector_type(8))) short short8;   // 8 bf16 (4 VGPR)
typedef __attribute__((ext_vector_type(4))) float floatx4;  // MFMA C/D

__device__ __forceinline__ ushortT f2bf(float f) {
    union { float f; unsigned int i; } c;
    c.f = f;
    unsigned int r = c.i + 0x7FFFu + ((c.i >> 16) & 1u);   // RNE
    return (ushortT)(r >> 16);
}

__device__ __forceinline__ uintT pack2(float lo, float hi) {
    return (uintT)f2bf(lo) | ((uintT)f2bf(hi) << 16);
}

__device__ __forceinline__ float4 f4fma(const float4 w, const float s, const float4 acc) {
    float4 r;
    r.x = fmaf(w.x, s, acc.x);
    r.y = fmaf(w.y, s, acc.y);
    r.z = fmaf(w.z, s, acc.z);
    r.w = fmaf(w.w, s, acc.w);
    return r;
}

// accumulate 8 bf16 (one uint4) into a[0..7]
__device__ __forceinline__ void acc8(const uint4 u, float* a) {
    a[0] += __uint_as_float(u.x << 16);
    a[1] += __uint_as_float(u.x & 0xFFFF0000u);
    a[2] += __uint_as_float(u.y << 16);
    a[3] += __uint_as_float(u.y & 0xFFFF0000u);
    a[4] += __uint_as_float(u.z << 16);
    a[5] += __uint_as_float(u.z & 0xFFFF0000u);
    a[6] += __uint_as_float(u.w << 16);
    a[7] += __uint_as_float(u.w & 0xFFFF0000u);
}

// a[0..7] += s * u (8 bf16)
__device__ __forceinline__ void fma8(const uint4 u, float s, float* a) {
    a[0] = fmaf(__uint_as_float(u.x << 16),          s, a[0]);
    a[1] = fmaf(__uint_as_float(u.x & 0xFFFF0000u),  s, a[1]);
    a[2] = fmaf(__uint_as_float(u.y << 16),          s, a[2]);
    a[3] = fmaf(__uint_as_float(u.y & 0xFFFF0000u),  s, a[3]);
    a[4] = fmaf(__uint_as_float(u.z << 16),          s, a[4]);
    a[5] = fmaf(__uint_as_float(u.z & 0xFFFF0000u),  s, a[5]);
    a[6] = fmaf(__uint_as_float(u.w << 16),          s, a[6]);
    a[7] = fmaf(__uint_as_float(u.w & 0xFFFF0000u),  s, a[7]);
}

// unpack 8 bf16 (uint4) to fp32
__device__ __forceinline__ void unp8(const uint4 u, float* a) {
    a[0] = __uint_as_float(u.x << 16);
    a[1] = __uint_as_float(u.x & 0xFFFF0000u);
    a[2] = __uint_as_float(u.y << 16);
    a[3] = __uint_as_float(u.y & 0xFFFF0000u);
    a[4] = __uint_as_float(u.z << 16);
    a[5] = __uint_as_float(u.z & 0xFFFF0000u);
    a[6] = __uint_as_float(u.w << 16);
    a[7] = __uint_as_float(u.w & 0xFFFF0000u);
}

// ---- weight transposes (fp32 [k][n] -> bf16 [n][k]) + zero stats+gcur ----
__global__ void k_wt(const float* __restrict__ W0, const float* __restrict__ W1,
                     ushortT* __restrict__ WT0, ushortT* __restrict__ WT1,
                     float* __restrict__ stats) {
    int i = blockIdx.x * 256 + threadIdx.x;   // 128 blocks x 256
    if (i < 1024) stats[i] = 0.f;             // stats[512] + gcur[512] (0 bits)
    int half = i >> 14, r = i & 16383;
    int n = r >> 7, k = r & 127;
    if (half == 0) WT0[r] = f2bf(W0[k * 128 + n]);
    else           WT1[r] = f2bf(W1[k * 128 + n]);
}

// ---- FUSED: edge LDS-binning (P1) + layer-0 matmul (unscaled) ------------
// 782 binning blocks x 2048 edges, 512-node bins (BINS=196): halves every
// per-block fixed loop vs 256-node bins, pad fraction 62%->35%, and the
// barrier-heavy LDS scan is replaced by a wave-shuffle scan (6 barriers
// total in the role, was ~22). LDS union ~20KB -> 8 blocks/CU.
// Binning: LDS-bin by dst>>9, reserve 64B-aligned runs via one global
// atomic per bin, coalesced flush, pad runs to 8 edges with sentinels
// (single writer per line -> cross-XCD safe).
// Grid 3907: idx%5==0 -> binning (782); else -> mm role (3125 blocks).
struct P1S {
    uint2 stage[EPB];    // binned (dst,src) pairs (16KB)
    int lcnt[BINS];
    int lbase[256];      // inclusive scan (1 entry/thread)
    int lcur[BINS];
    int goff[BINS];
    int wsum[4];
};
union SMu {
    P1S p1;
    ushortT xs[32 * 136];
};

__global__ __launch_bounds__(256)
void k_p1(const int* __restrict__ src, const int* __restrict__ dst,
          uint2* __restrict__ gbin, int* __restrict__ gcur,
          const float* __restrict__ x, const ushortT* __restrict__ WT,
          ushortT* __restrict__ outb)
{
    __shared__ SMu sm;
    const int idx = blockIdx.x;
    const int tid = threadIdx.x;
    const int d5 = idx / 5;
    if (idx - 5 * d5 == 0) {
        // ---------------- P1 binning role ----------------
        P1S& S = sm.p1;
        const int e00 = d5 * EPB;
        if (tid < BINS) S.lcnt[tid] = 0;
        __syncthreads();
        int4 dv[2], sv[2];
        bool val[2];
        #pragma unroll
        for (int i = 0; i < 2; ++i) {
            int e0 = e00 + i * 1024 + tid * 4;
            val[i] = (e0 < NE);              // e0%4==0, NE%4==0 -> quad in-bounds
            if (val[i]) {
                dv[i] = *(const int4*)(dst + e0);
                sv[i] = *(const int4*)(src + e0);
                atomicAdd(&S.lcnt[dv[i].x >> 9], 1);
                atomicAdd(&S.lcnt[dv[i].y >> 9], 1);
                atomicAdd(&S.lcnt[dv[i].z >> 9], 1);
                atomicAdd(&S.lcnt[dv[i].w >> 9], 1);
            }
        }
        __syncthreads();
        // inclusive scan over 196 bins: wave shfl scan + cross-wave fix
        int v = (tid < BINS) ? S.lcnt[tid] : 0;
        #pragma unroll
        for (int dd = 1; dd < 64; dd <<= 1) {
            int t = __shfl_up(v, dd);
            if ((tid & 63) >= dd) v += t;
        }
        if ((tid & 63) == 63) S.wsum[tid >> 6] = v;
        __syncthreads();
        if (tid >= 64) {
            int off = S.wsum[0];
            if (tid >= 128) off += S.wsum[1];
            if (tid >= 192) off += S.wsum[2];
            v += off;
        }
        S.lbase[tid] = v;                          // inclusive scan
        if (tid < BINS) S.lcur[tid] = v - S.lcnt[tid];   // exclusive prefix
        __syncthreads();
        // place into LDS stage, bin-grouped
        #pragma unroll
        for (int i = 0; i < 2; ++i) {
            if (val[i]) {
                int p;
                p = atomicAdd(&S.lcur[dv[i].x >> 9], 1);
                S.stage[p] = make_uint2((uintT)dv[i].x, (uintT)sv[i].x);
                p = atomicAdd(&S.lcur[dv[i].y >> 9], 1);
                S.stage[p] = make_uint2((uintT)dv[i].y, (uintT)sv[i].y);
                p = atomicAdd(&S.lcur[dv[i].z >> 9], 1);
                S.stage[p] = make_uint2((uintT)dv[i].z, (uintT)sv[i].z);
                p = atomicAdd(&S.lcur[dv[i].w >> 9], 1);
                S.stage[p] = make_uint2((uintT)dv[i].w, (uintT)sv[i].w);
            }
        }
        __syncthreads();
        // reserve 64B-aligned runs (8-edge units) per nonempty bin
        if (tid < BINS) {
            int c = S.lcnt[tid];
            int r = (c + 7) & ~7;
            S.goff[tid] = r ? atomicAdd(&gcur[tid], r) : 0;
        }
        __syncthreads();
        const int total = S.lbase[BINS - 1];
        // coalesced flush: consecutive p -> mostly consecutive gbin addresses
        for (int p = tid; p < total; p += 256) {
            uint2 e = S.stage[p];
            int bin = (int)(e.x >> 9);
            int eb = bin ? S.lbase[bin - 1] : 0;
            int gpos = S.goff[bin] + (p - eb);
            if (gpos < CAP) gbin[(size_t)bin * CAP + gpos] = e;
        }
        // sentinel pads (within this block's exclusive lines)
        if (tid < BINS) {
            int c = S.lcnt[tid];
            int r = (c + 7) & ~7;
            for (int q = c; q < r; ++q) {
                int gpos = S.goff[tid] + q;
                if (gpos < CAP) gbin[(size_t)tid * CAP + gpos] = make_uint2(0xFFFFFFFFu, 0u);
            }
        }
        return;
    }
    // ---------------- mm role: h0 = bf16(x @ W0), UNSCALED ----------------
    const int m = idx - d5 - 1;              // 0..3124 consecutive
    ushortT* XS = sm.xs;
    const int row0 = m * 32;

    #pragma unroll
    for (int i = 0; i < 4; ++i) {
        int id2 = tid + 256 * i;       // float4 index over 32 rows x 32
        int rr = id2 >> 5, c4 = id2 & 31;
        int grow = row0 + rr;
        float4 v = {0.f, 0.f, 0.f, 0.f};
        if (grow < NN) v = ((const float4*)(x + (size_t)grow * DIM))[c4];
        ushort4 o;
        o.x = f2bf(v.x); o.y = f2bf(v.y); o.z = f2bf(v.z); o.w = f2bf(v.w);
        *(ushort4*)(XS + rr * 136 + c4 * 4) = o;
    }
    __syncthreads();

    const int w    = tid >> 6;
    const int lane = tid & 63;
    const int q    = lane >> 4;
    const int mr   = lane & 15;
    const int rw   = (w >> 1) * 16;    // row half
    const int ch   = (w & 1) * 64;     // col half

    floatx4 acc[4];
    #pragma unroll
    for (int t = 0; t < 4; ++t) { acc[t][0] = 0.f; acc[t][1] = 0.f; acc[t][2] = 0.f; acc[t][3] = 0.f; }

    #pragma unroll
    for (int c = 0; c < 4; ++c) {
        short8 a = *(const short8*)(XS + (rw + mr) * 136 + c * 32 + q * 8);
        #pragma unroll
        for (int t = 0; t < 4; ++t) {
            short8 b = *(const short8*)(WT + (size_t)(ch + t * 16 + mr) * 128 + c * 32 + q * 8);
            acc[t] = __builtin_amdgcn_mfma_f32_16x16x32_bf16(a, b, acc[t], 0, 0, 0);
        }
    }

    #pragma unroll
    for (int rr = 0; rr < 4; ++rr) {
        int grow = row0 + rw + q * 4 + rr;
        if (grow < NN) {
            #pragma unroll
            for (int t = 0; t < 4; ++t)
                outb[(size_t)grow * DIM + ch + t * 16 + mr] = f2bf(acc[t][rr]);
        }
    }
}

// ---- P2: per-bin bucket build. One block OWNS one 512-node bin's bucket --
// window (128KB, L2-resident): slots via LDS atomics (no global atomics),
// plain stores (exclusive ownership -> cross-XCD safe). Emits cnt + dinv.
__global__ __launch_bounds__(512)
void k_p2(const uint2* __restrict__ gbin, const int* __restrict__ gcur,
          int* __restrict__ bucket, int* __restrict__ cnt,
          float* __restrict__ dinv)
{
    __shared__ int lc[512];
    const int b = blockIdx.x;
    const int tid = threadIdx.x;
    lc[tid] = 0;
    __syncthreads();
    int cb = gcur[b];
    if (cb > CAP) cb = CAP;
    const uint2* gb = gbin + (size_t)b * CAP;
    for (int p = tid; p < cb; p += 512) {
        uint2 e = gb[p];
        if (e.x != 0xFFFFFFFFu) {
            int slot = atomicAdd(&lc[e.x & 511], 1);
            if (slot < BK) bucket[(size_t)e.x * BK + slot] = (int)e.y;
        }
    }
    __syncthreads();
    {
        int n = b * 512 + tid;
        if (n < NN) {
            int d = lc[tid];
            cnt[n] = d;
            dinv[n] = rsqrtf((float)d + 1.0f);   // deg includes self-loop (+1)
        }
    }
}

// ---- bucket-CSR aggregation, 128 bf16 features: wave = 4 edges x 16 lanes
// MLP-4 gathers (4 in flight, occupancy-neutral). NO nontemporal hints:
// round-8 A/B showed they RAISE FETCH (192.6->201.7MB) and cost 4 VGPR.
// EDGE_SCALE: h unscaled -> multiply per-edge by dinv[src] (400KB, L2-hot).
// out = dinv[n]*(sum + self) + bias; BN stats fused.
template <bool EDGE_SCALE>
__global__ __launch_bounds__(256)
void k_agg_wide(const ushortT* __restrict__ hb, const int* __restrict__ cnt,
                const int* __restrict__ bucket, const float* __restrict__ dinv,
                const float* __restrict__ bias, ushortT* __restrict__ outBb,
                float* __restrict__ stats)
{
    const int lane = threadIdx.x & 63;
    const int w    = threadIdx.x >> 6;
    const int sg   = lane >> 4;      // edge slot within group of 4
    const int f    = lane & 15;      // 16B feature octet (features f*8..f*8+7)
    const int wid  = blockIdx.x * 4 + w;
    const int nW   = gridDim.x * 4;
    const uint4* h4 = (const uint4*)hb;   // row = 16 x uint4

    float bl[8];
    #pragma unroll
    for (int i = 0; i < 8; ++i) bl[i] = bias[f * 8 + i];

    float ssum[8], ssq[8];
    #pragma unroll
    for (int i = 0; i < 8; ++i) { ssum[i] = 0.f; ssq[i] = 0.f; }

    for (int n = wid; n < NN; n += nW) {
        int d = cnt[n];
        if (d > BK) d = BK;
        const int* bp = bucket + (size_t)n * BK;
        float a[8];
        #pragma unroll
        for (int i = 0; i < 8; ++i) a[i] = 0.f;

        int j = 0;
        // 16-slot chunks: 4 gathers in flight per lane
        for (; j + 16 <= d; j += 16) {
            int4 pv = *(const int4*)(bp + j + 4 * sg);
            uint4 u0 = h4[(size_t)pv.x * 16 + f];
            uint4 u1 = h4[(size_t)pv.y * 16 + f];
            uint4 u2 = h4[(size_t)pv.z * 16 + f];
            uint4 u3 = h4[(size_t)pv.w * 16 + f];
            if (EDGE_SCALE) {
                float d0 = dinv[pv.x], d1 = dinv[pv.y];
                float d2 = dinv[pv.z], d3 = dinv[pv.w];
                fma8(u0, d0, a);
                fma8(u1, d1, a);
                fma8(u2, d2, a);
                fma8(u3, d3, a);
            } else {
                acc8(u0, a);
                acc8(u1, a);
                acc8(u2, a);
                acc8(u3, a);
            }
        }
        // 8-slot chunks: 2 gathers in flight
        for (; j + 8 <= d; j += 8) {
            int s0 = bp[j + sg];
            int s1 = bp[j + 4 + sg];
            uint4 u0 = h4[(size_t)s0 * 16 + f];
            uint4 u1 = h4[(size_t)s1 * 16 + f];
            if (EDGE_SCALE) {
                float d0 = dinv[s0], d1 = dinv[s1];
                fma8(u0, d0, a);
                fma8(u1, d1, a);
            } else {
                acc8(u0, a);
                acc8(u1, a);
            }
        }
        // tail
        for (; j < d; j += 4) {
            int e = j + sg;
            if (e < d) {
                int s0 = bp[e];
                uint4 u = h4[(size_t)s0 * 16 + f];
                if (EDGE_SCALE) fma8(u, dinv[s0], a);
                else            acc8(u, a);
            }
        }
        #pragma unroll
        for (int i = 0; i < 8; ++i) {
            a[i] += __shfl_xor(a[i], 16);
            a[i] += __shfl_xor(a[i], 32);
        }
        if (lane < 16) {
            uint4 us = h4[(size_t)n * 16 + f];   // self row
            float di = dinv[n];
            if (EDGE_SCALE) fma8(us, di, a);     // self contributes dinv[n]*h[n]
            else            acc8(us, a);
            float v[8];
            #pragma unroll
            for (int i = 0; i < 8; ++i) v[i] = fmaf(di, a[i], bl[i]);
            uint4 o;
            o.x = pack2(v[0], v[1]);
            o.y = pack2(v[2], v[3]);
            o.z = pack2(v[4], v[5]);
            o.w = pack2(v[6], v[7]);
            ((uint4*)(outBb + (size_t)n * DIM))[f] = o;
            #pragma unroll
            for (int i = 0; i < 8; ++i) {
                ssum[i] += v[i];
                ssq[i]  = fmaf(v[i], v[i], ssq[i]);
            }
        }
    }

    __shared__ float ls[4 * 128], lq[4 * 128];
    if (lane < 16) {
        #pragma unroll
        for (int i = 0; i < 8; ++i) {
            ls[w * 128 + f * 8 + i] = ssum[i];
            lq[w * 128 + f * 8 + i] = ssq[i];
        }
    }
    __syncthreads();
    int t = threadIdx.x;
    if (t < 128) {
        float a = ls[t] + ls[128 + t] + ls[256 + t] + ls[384 + t];
        float b = lq[t] + lq[128 + t] + lq[256 + t] + lq[384 + t];
        unsafeAtomicAdd(&stats[t], a);
        unsafeAtomicAdd(&stats[128 + t], b);
    }
}

// ---- MFMA bf16 matmul 128x128, layer 1: BN coef in-kernel, out *= dinv ---
__global__ __launch_bounds__(256)
void k_mm128_l1(const ushortT* __restrict__ inb, const ushortT* __restrict__ WT,
                const float* __restrict__ stats, const float* __restrict__ g,
                const float* __restrict__ be, const float* __restrict__ dinv,
                ushortT* __restrict__ outb)
{
    __shared__ ushortT XS[64 * 136];
    __shared__ float CA[128], CD[128];
    const int tid  = threadIdx.x;
    const int row0 = blockIdx.x * 64;

    if (tid < 128) {
        float mu  = stats[tid] * INVN;
        float var = stats[128 + tid] * INVN - mu * mu;
        float a = g[tid] * rsqrtf(var + BN_EPS);
        CA[tid] = a;
        CD[tid] = be[tid] - mu * a;
    }
    __syncthreads();

    #pragma unroll
    for (int i = 0; i < 4; ++i) {
        int idx = tid + 256 * i;       // uint4 (8 bf16) index: 64 rows x 16
        int r = idx >> 4, c8 = idx & 15;
        int grow = row0 + r;
        uint4 u = {0, 0, 0, 0};
        if (grow < NN) u = ((const uint4*)(inb + (size_t)grow * DIM))[c8];
        float v[8];
        unp8(u, v);
        #pragma unroll
        for (int k = 0; k < 8; ++k)
            v[k] = fmaxf(0.f, fmaf(v[k], CA[c8 * 8 + k], CD[c8 * 8 + k]));
        uint4 o;
        o.x = pack2(v[0], v[1]);
        o.y = pack2(v[2], v[3]);
        o.z = pack2(v[4], v[5]);
        o.w = pack2(v[6], v[7]);
        *(uint4*)(XS + r * 136 + c8 * 8) = o;
    }
    __syncthreads();

    const int w    = tid >> 6;
    const int lane = tid & 63;
    const int q    = lane >> 4;
    const int mr   = lane & 15;
    const int rw   = w * 16;

    floatx4 acc[8];
    #pragma unroll
    for (int t = 0; t < 8; ++t) { acc[t][0] = 0.f; acc[t][1] = 0.f; acc[t][2] = 0.f; acc[t][3] = 0.f; }

    #pragma unroll
    for (int c = 0; c < 4; ++c) {
        short8 a = *(const short8*)(XS + (rw + mr) * 136 + c * 32 + q * 8);
        #pragma unroll
        for (int t = 0; t < 8; ++t) {
            short8 b = *(const short8*)(WT + (size_t)(t * 16 + mr) * 128 + c * 32 + q * 8);
            acc[t] = __builtin_amdgcn_mfma_f32_16x16x32_bf16(a, b, acc[t], 0, 0, 0);
        }
    }

    #pragma unroll
    for (int r = 0; r < 4; ++r) {
        int grow = row0 + rw + q * 4 + r;
        if (grow < NN) {
            float di = dinv[grow];
            #pragma unroll
            for (int t = 0; t < 8; ++t) {
                outb[(size_t)grow * DIM + t * 16 + mr] = f2bf(acc[t][r] * di);
            }
        }
    }
}

// ---- layer-2 matmul 128->10, BN coef in-kernel, bf16 16-col out ----------
__global__ __launch_bounds__(128)
void k_mm_l2(const ushortT* __restrict__ inb, const float* __restrict__ W2,
             const float* __restrict__ stats, const float* __restrict__ g,
             const float* __restrict__ be, const float* __restrict__ dinv,
             ushortT* __restrict__ Cb)
{
    __shared__ float WL[128 * 16];   // cols padded 10->16 with zeros
    __shared__ float XS[32 * 128];
    __shared__ float CA[128], CD[128];
    const int tid  = threadIdx.x;
    const int row0 = blockIdx.x * 32;

    {
        float mu  = stats[tid] * INVN;
        float var = stats[128 + tid] * INVN - mu * mu;
        float a = g[tid] * rsqrtf(var + BN_EPS);
        CA[tid] = a;
        CD[tid] = be[tid] - mu * a;
    }
    for (int idx = tid; idx < 128 * 16; idx += 128) {
        int k = idx >> 4, c = idx & 15;
        WL[idx] = (c < OC) ? W2[k * OC + c] : 0.0f;
    }
    __syncthreads();

    #pragma unroll
    for (int i = 0; i < 4; ++i) {
        int idx = tid + 128 * i;       // uint4 (8 bf16): 32 rows x 16
        int r = idx >> 4, c8 = idx & 15;
        uint4 u = ((const uint4*)(inb + (size_t)(row0 + r) * DIM))[c8];
        float v[8];
        unp8(u, v);
        float* xp = XS + r * 128 + c8 * 8;
        #pragma unroll
        for (int k = 0; k < 8; ++k)
            xp[k] = fmaxf(0.f, fmaf(v[k], CA[c8 * 8 + k], CD[c8 * 8 + k]));
    }
    __syncthreads();

    const int cg = tid & 3;
    const int rg = tid >> 2;
    float4 acc = {0, 0, 0, 0};
    const float4* XS4 = (const float4*)XS;
    const float4* WL4 = (const float4*)WL;
    for (int k = 0; k < 128; k += 4) {
        float4 w0 = WL4[(k + 0) * 4 + cg];
        float4 w1 = WL4[(k + 1) * 4 + cg];
        float4 w2 = WL4[(k + 2) * 4 + cg];
        float4 w3 = WL4[(k + 3) * 4 + cg];
        float4 x = XS4[rg * 32 + (k >> 2)];
        acc = f4fma(w0, x.x, f4fma(w1, x.y, f4fma(w2, x.z, f4fma(w3, x.w, acc))));
    }
    float di = dinv[row0 + rg];
    uint2 o;
    o.x = pack2(acc.x * di, acc.y * di);
    o.y = pack2(acc.z * di, acc.w * di);
    ((uint2*)(Cb + ((size_t)row0 + rg) * 16))[cg] = o;   // padded cols are 0
}

// ---- bucket-CSR aggregation, 10 bf16 features: wave = 8 edges x 8 lanes --
__global__ __launch_bounds__(256)
void k_agg10(const ushortT* __restrict__ Cb, const int* __restrict__ cnt,
             const int* __restrict__ bucket, const float* __restrict__ dinv,
             const float* __restrict__ b2, float* __restrict__ out)
{
    const int lane = threadIdx.x & 63;
    const int sg   = lane >> 3;      // edge slot 0..7
    const int f    = lane & 7;       // feature pair (cols 2f, 2f+1)
    const int wid  = (blockIdx.x * 256 + threadIdx.x) >> 6;
    const int nW   = gridDim.x * 4;
    const uintT* Cu = (const uintT*)Cb;   // row = 8 uints

    for (int n = wid; n < NN; n += nW) {
        int d = cnt[n];
        if (d > BK) d = BK;
        const int* bp = bucket + (size_t)n * BK;
        float a0 = 0.f, a1 = 0.f;
        for (int j = sg; j < d; j += 8) {
            uintT u = Cu[(size_t)bp[j] * 8 + f];
            a0 += __uint_as_float(u << 16);
            a1 += __uint_as_float(u & 0xFFFF0000u);
        }
        a0 += __shfl_xor(a0, 8);  a1 += __shfl_xor(a1, 8);
        a0 += __shfl_xor(a0, 16); a1 += __shfl_xor(a1, 16);
        a0 += __shfl_xor(a0, 32); a1 += __shfl_xor(a1, 32);
        if (lane < 8) {
            uintT us = Cu[(size_t)n * 8 + f];   // self row
            a0 += __uint_as_float(us << 16);
            a1 += __uint_as_float(us & 0xFFFF0000u);
            float di = dinv[n];
            if (2 * f < OC) {
                float2 o;
                o.x = fmaf(di, a0, b2[2 * f]);
                o.y = fmaf(di, a1, b2[2 * f + 1]);
                *(float2*)(out + (size_t)n * OC + 2 * f) = o;
            }
        }
    }
}

extern "C" void kernel_launch(void* const* d_in, const int* in_sizes, int n_in,
                              void* d_out, int out_size, void* d_ws, size_t ws_size,
                              hipStream_t stream) {
    const float* x    = (const float*)d_in[0];
    const int*   ei   = (const int*)d_in[1];
    const int*   srcv = ei;          // row 0
    const int*   dstv = ei + NE;     // row 1
    const float* W0  = (const float*)d_in[2];
    const float* b0  = (const float*)d_in[3];
    const float* g0  = (const float*)d_in[4];
    const float* be0 = (const float*)d_in[5];
    const float* W1  = (const float*)d_in[6];
    const float* b1  = (const float*)d_in[7];
    const float* g1  = (const float*)d_in[8];
    const float* be1 = (const float*)d_in[9];
    const float* W2  = (const float*)d_in[10];
    const float* b2  = (const float*)d_in[11];
    float* out = (float*)d_out;

    // workspace layout (4-byte words), ~77.7 MB total
    float* base   = (float*)d_ws;
    int*   cnt    = (int*)base;                    // NN (true degree)
    float* dinv   = base + NN;                     // NN
    float* stats  = base + 2 * NN;                 // 512 (L0: +0, L1: +256)
    int*   gcur   = (int*)(stats + 512);           // 512 (BINS used, zeroed by k_wt)
    ushortT* WT0  = (ushortT*)(base + 2 * NN + 1024);      // 8192 words
    ushortT* WT1  = (ushortT*)(base + 2 * NN + 9216);      // 8192 words
    int*   bucket = (int*)(base + 2 * NN + 17408);         // NN*BK ints (64B-aligned)
    ushortT* A_bf = (ushortT*)(base + 2 * NN + 17408 + (size_t)NN * BK);  // NN*64 words
    ushortT* B_bf = A_bf + (size_t)NN * DIM;               // NN*128 bf16
    ushortT* Cb   = A_bf;                          // layer-2 h2' bf16 (aliases A_bf)
    uint2* gbin   = (uint2*)B_bf;                  // 196*16320*8B <= B_bf, freed before agg0

    // weight transposes + stats/gcur zero (independent of graph)
    k_wt<<<128, 256, 0, stream>>>(W0, W1, WT0, WT1, stats);

    // fused: edge binning (782 blocks) + layer-0 matmul (3125 blocks)
    k_p1<<<P1B + 3125, 256, 0, stream>>>(srcv, dstv, gbin, gcur, x, WT0, A_bf);
    // per-bin bucket build + cnt + dinv
    k_p2<<<BINS, 512, 0, stream>>>(gbin, gcur, bucket, cnt, dinv);

    // ---- layer 0: h unscaled -> per-edge dinv[src] scaling in agg ----
    k_agg_wide<true><<<2048, 256, 0, stream>>>(A_bf, cnt, bucket, dinv, b0, B_bf, stats);

    // ---- layer 1 (BN coef from stats computed in-kernel; out pre-scaled) ----
    k_mm128_l1<<<(NN + 63) / 64, 256, 0, stream>>>(B_bf, WT1, stats, g0, be0, dinv, A_bf);
    k_agg_wide<false><<<2048, 256, 0, stream>>>(A_bf, cnt, bucket, dinv, b1, B_bf, stats + 256);

    // ---- layer 2: project to 10 dims first, aggregate cheap ----
    k_mm_l2<<<NN / 32, 128, 0, stream>>>(B_bf, W2, stats + 256, g1, be1, dinv, Cb);
    k_agg10<<<1024, 256, 0, stream>>>(Cb, cnt, bucket, dinv, b2, out);
}

// Round 11
// 481.821 us; speedup vs baseline: 1.0307x; 1.0307x over previous
//
#include <hip/hip_runtime.h>
#include <hip/hip_bf16.h>

// Problem constants (match reference)
static constexpr int NN  = 100000;   // nodes
static constexpr int NE  = 1600000;  // edges
static constexpr int DIM = 128;
static constexpr int OC  = 10;
static constexpr int BK  = 64;       // bucket capacity (max deg ~45 for Poisson(16))
static constexpr float BN_EPS = 1e-5f;
static constexpr float INVN   = 1.0f / (float)NN;

// edge binning: bin = dst>>9 (512 nodes/bin); per-bin buffer capacity
static constexpr int BINS = 196;     // ceil(100000/512)
static constexpr int CAP  = 16320;   // slots/bin (mult of 8); 196*16320*8B = 25.59MB fits B_bf
static constexpr int EPB  = 2048;    // edges per binning block
static constexpr int P1B  = (NE + EPB - 1) / EPB;   // 782 binning blocks

typedef unsigned short ushortT;
typedef unsigned int uintT;
typedef __attribute__((ext_vector_type(8))) short short8;   // 8 bf16 (4 VGPR)
typedef __attribute__((ext_vector_type(4))) float floatx4;  // MFMA C/D

__device__ __forceinline__ ushortT f2bf(float f) {
    union { float f; unsigned int i; } c;
    c.f = f;
    unsigned int r = c.i + 0x7FFFu + ((c.i >> 16) & 1u);   // RNE
    return (ushortT)(r >> 16);
}

__device__ __forceinline__ uintT pack2(float lo, float hi) {
    return (uintT)f2bf(lo) | ((uintT)f2bf(hi) << 16);
}

__device__ __forceinline__ float4 f4fma(const float4 w, const float s, const float4 acc) {
    float4 r;
    r.x = fmaf(w.x, s, acc.x);
    r.y = fmaf(w.y, s, acc.y);
    r.z = fmaf(w.z, s, acc.z);
    r.w = fmaf(w.w, s, acc.w);
    return r;
}

// accumulate 8 bf16 (one uint4) into a[0..7]
__device__ __forceinline__ void acc8(const uint4 u, float* a) {
    a[0] += __uint_as_float(u.x << 16);
    a[1] += __uint_as_float(u.x & 0xFFFF0000u);
    a[2] += __uint_as_float(u.y << 16);
    a[3] += __uint_as_float(u.y & 0xFFFF0000u);
    a[4] += __uint_as_float(u.z << 16);
    a[5] += __uint_as_float(u.z & 0xFFFF0000u);
    a[6] += __uint_as_float(u.w << 16);
    a[7] += __uint_as_float(u.w & 0xFFFF0000u);
}

// a[0..7] += s * u (8 bf16)
__device__ __forceinline__ void fma8(const uint4 u, float s, float* a) {
    a[0] = fmaf(__uint_as_float(u.x << 16),          s, a[0]);
    a[1] = fmaf(__uint_as_float(u.x & 0xFFFF0000u),  s, a[1]);
    a[2] = fmaf(__uint_as_float(u.y << 16),          s, a[2]);
    a[3] = fmaf(__uint_as_float(u.y & 0xFFFF0000u),  s, a[3]);
    a[4] = fmaf(__uint_as_float(u.z << 16),          s, a[4]);
    a[5] = fmaf(__uint_as_float(u.z & 0xFFFF0000u),  s, a[5]);
    a[6] = fmaf(__uint_as_float(u.w << 16),          s, a[6]);
    a[7] = fmaf(__uint_as_float(u.w & 0xFFFF0000u),  s, a[7]);
}

// unpack 8 bf16 (uint4) to fp32
__device__ __forceinline__ void unp8(const uint4 u, float* a) {
    a[0] = __uint_as_float(u.x << 16);
    a[1] = __uint_as_float(u.x & 0xFFFF0000u);
    a[2] = __uint_as_float(u.y << 16);
    a[3] = __uint_as_float(u.y & 0xFFFF0000u);
    a[4] = __uint_as_float(u.z << 16);
    a[5] = __uint_as_float(u.z & 0xFFFF0000u);
    a[6] = __uint_as_float(u.w << 16);
    a[7] = __uint_as_float(u.w & 0xFFFF0000u);
}

// ---- weight transposes (fp32 [k][n] -> bf16 [n][k]) + zero stats+gcur ----
__global__ void k_wt(const float* __restrict__ W0, const float* __restrict__ W1,
                     ushortT* __restrict__ WT0, ushortT* __restrict__ WT1,
                     float* __restrict__ stats) {
    int i = blockIdx.x * 256 + threadIdx.x;   // 128 blocks x 256
    if (i < 1024) stats[i] = 0.f;             // stats[512] + gcur[512] (0 bits)
    int half = i >> 14, r = i & 16383;
    int n = r >> 7, k = r & 127;
    if (half == 0) WT0[r] = f2bf(W0[k * 128 + n]);
    else           WT1[r] = f2bf(W1[k * 128 + n]);
}

// ---- FUSED: edge LDS-binning (P1) + layer-0 matmul (unscaled) ------------
// 782 binning blocks x 2048 edges, 512-node bins (BINS=196); wave-shuffle
// scan (6 barriers in the role). LDS union ~20KB -> 8 blocks/CU.
// Binning: LDS-bin by dst>>9, reserve 64B-aligned runs via one global
// atomic per bin, coalesced flush, pad runs to 8 edges with sentinels
// (single writer per line -> cross-XCD safe).
// Grid 3907: idx%5==0 -> binning (782); else -> mm role (3125 blocks).
struct P1S {
    uint2 stage[EPB];    // binned (dst,src) pairs (16KB)
    int lcnt[BINS];
    int lbase[256];      // inclusive scan (1 entry/thread)
    int lcur[BINS];
    int goff[BINS];
    int wsum[4];
};
union SMu {
    P1S p1;
    ushortT xs[32 * 136];
};

__global__ __launch_bounds__(256)
void k_p1(const int* __restrict__ src, const int* __restrict__ dst,
          uint2* __restrict__ gbin, int* __restrict__ gcur,
          const float* __restrict__ x, const ushortT* __restrict__ WT,
          ushortT* __restrict__ outb)
{
    __shared__ SMu sm;
    const int idx = blockIdx.x;
    const int tid = threadIdx.x;
    const int d5 = idx / 5;
    if (idx - 5 * d5 == 0) {
        // ---------------- P1 binning role ----------------
        P1S& S = sm.p1;
        const int e00 = d5 * EPB;
        if (tid < BINS) S.lcnt[tid] = 0;
        __syncthreads();
        int4 dv[2], sv[2];
        bool val[2];
        #pragma unroll
        for (int i = 0; i < 2; ++i) {
            int e0 = e00 + i * 1024 + tid * 4;
            val[i] = (e0 < NE);              // e0%4==0, NE%4==0 -> quad in-bounds
            if (val[i]) {
                dv[i] = *(const int4*)(dst + e0);
                sv[i] = *(const int4*)(src + e0);
                atomicAdd(&S.lcnt[dv[i].x >> 9], 1);
                atomicAdd(&S.lcnt[dv[i].y >> 9], 1);
                atomicAdd(&S.lcnt[dv[i].z >> 9], 1);
                atomicAdd(&S.lcnt[dv[i].w >> 9], 1);
            }
        }
        __syncthreads();
        // inclusive scan over 196 bins: wave shfl scan + cross-wave fix
        int v = (tid < BINS) ? S.lcnt[tid] : 0;
        #pragma unroll
        for (int dd = 1; dd < 64; dd <<= 1) {
            int t = __shfl_up(v, dd);
            if ((tid & 63) >= dd) v += t;
        }
        if ((tid & 63) == 63) S.wsum[tid >> 6] = v;
        __syncthreads();
        if (tid >= 64) {
            int off = S.wsum[0];
            if (tid >= 128) off += S.wsum[1];
            if (tid >= 192) off += S.wsum[2];
            v += off;
        }
        S.lbase[tid] = v;                          // inclusive scan
        if (tid < BINS) S.lcur[tid] = v - S.lcnt[tid];   // exclusive prefix
        __syncthreads();
        // place into LDS stage, bin-grouped
        #pragma unroll
        for (int i = 0; i < 2; ++i) {
            if (val[i]) {
                int p;
                p = atomicAdd(&S.lcur[dv[i].x >> 9], 1);
                S.stage[p] = make_uint2((uintT)dv[i].x, (uintT)sv[i].x);
                p = atomicAdd(&S.lcur[dv[i].y >> 9], 1);
                S.stage[p] = make_uint2((uintT)dv[i].y, (uintT)sv[i].y);
                p = atomicAdd(&S.lcur[dv[i].z >> 9], 1);
                S.stage[p] = make_uint2((uintT)dv[i].z, (uintT)sv[i].z);
                p = atomicAdd(&S.lcur[dv[i].w >> 9], 1);
                S.stage[p] = make_uint2((uintT)dv[i].w, (uintT)sv[i].w);
            }
        }
        __syncthreads();
        // reserve 64B-aligned runs (8-edge units) per nonempty bin
        if (tid < BINS) {
            int c = S.lcnt[tid];
            int r = (c + 7) & ~7;
            S.goff[tid] = r ? atomicAdd(&gcur[tid], r) : 0;
        }
        __syncthreads();
        const int total = S.lbase[BINS - 1];
        // coalesced flush: consecutive p -> mostly consecutive gbin addresses
        for (int p = tid; p < total; p += 256) {
            uint2 e = S.stage[p];
            int bin = (int)(e.x >> 9);
            int eb = bin ? S.lbase[bin - 1] : 0;
            int gpos = S.goff[bin] + (p - eb);
            if (gpos < CAP) gbin[(size_t)bin * CAP + gpos] = e;
        }
        // sentinel pads (within this block's exclusive lines)
        if (tid < BINS) {
            int c = S.lcnt[tid];
            int r = (c + 7) & ~7;
            for (int q = c; q < r; ++q) {
                int gpos = S.goff[tid] + q;
                if (gpos < CAP) gbin[(size_t)tid * CAP + gpos] = make_uint2(0xFFFFFFFFu, 0u);
            }
        }
        return;
    }
    // ---------------- mm role: h0 = bf16(x @ W0), UNSCALED ----------------
    const int m = idx - d5 - 1;              // 0..3124 consecutive
    ushortT* XS = sm.xs;
    const int row0 = m * 32;

    #pragma unroll
    for (int i = 0; i < 4; ++i) {
        int id2 = tid + 256 * i;       // float4 index over 32 rows x 32
        int rr = id2 >> 5, c4 = id2 & 31;
        int grow = row0 + rr;
        float4 v = {0.f, 0.f, 0.f, 0.f};
        if (grow < NN) v = ((const float4*)(x + (size_t)grow * DIM))[c4];
        ushort4 o;
        o.x = f2bf(v.x); o.y = f2bf(v.y); o.z = f2bf(v.z); o.w = f2bf(v.w);
        *(ushort4*)(XS + rr * 136 + c4 * 4) = o;
    }
    __syncthreads();

    const int w    = tid >> 6;
    const int lane = tid & 63;
    const int q    = lane >> 4;
    const int mr   = lane & 15;
    const int rw   = (w >> 1) * 16;    // row half
    const int ch   = (w & 1) * 64;     // col half

    floatx4 acc[4];
    #pragma unroll
    for (int t = 0; t < 4; ++t) { acc[t][0] = 0.f; acc[t][1] = 0.f; acc[t][2] = 0.f; acc[t][3] = 0.f; }

    #pragma unroll
    for (int c = 0; c < 4; ++c) {
        short8 a = *(const short8*)(XS + (rw + mr) * 136 + c * 32 + q * 8);
        #pragma unroll
        for (int t = 0; t < 4; ++t) {
            short8 b = *(const short8*)(WT + (size_t)(ch + t * 16 + mr) * 128 + c * 32 + q * 8);
            acc[t] = __builtin_amdgcn_mfma_f32_16x16x32_bf16(a, b, acc[t], 0, 0, 0);
        }
    }

    #pragma unroll
    for (int rr = 0; rr < 4; ++rr) {
        int grow = row0 + rw + q * 4 + rr;
        if (grow < NN) {
            #pragma unroll
            for (int t = 0; t < 4; ++t)
                outb[(size_t)grow * DIM + ch + t * 16 + mr] = f2bf(acc[t][rr]);
        }
    }
}

// ---- P2: per-bin bucket build. One block OWNS one 512-node bin's bucket --
// window (128KB, L2-resident): slots via LDS atomics (no global atomics),
// plain stores (exclusive ownership -> cross-XCD safe). Emits cnt + dinv.
__global__ __launch_bounds__(512)
void k_p2(const uint2* __restrict__ gbin, const int* __restrict__ gcur,
          int* __restrict__ bucket, int* __restrict__ cnt,
          float* __restrict__ dinv)
{
    __shared__ int lc[512];
    const int b = blockIdx.x;
    const int tid = threadIdx.x;
    lc[tid] = 0;
    __syncthreads();
    int cb = gcur[b];
    if (cb > CAP) cb = CAP;
    const uint2* gb = gbin + (size_t)b * CAP;
    for (int p = tid; p < cb; p += 512) {
        uint2 e = gb[p];
        if (e.x != 0xFFFFFFFFu) {
            int slot = atomicAdd(&lc[e.x & 511], 1);
            if (slot < BK) bucket[(size_t)e.x * BK + slot] = (int)e.y;
        }
    }
    __syncthreads();
    {
        int n = b * 512 + tid;
        if (n < NN) {
            int d = lc[tid];
            cnt[n] = d;
            dinv[n] = rsqrtf((float)d + 1.0f);   // deg includes self-loop (+1)
        }
    }
}

// ---- bucket-CSR aggregation, 128 bf16 features: wave = 4 edges x 16 lanes
// MLP-4 gathers (4 in flight, occupancy-neutral). NO nontemporal hints
// (round-8 A/B: they RAISE FETCH and cost 4 VGPR). UNCHANGED from r9/r10:
// measured at the request-pattern ceiling (223MB @ 2.07 TB/s = 108us floor
// vs 110.5 observed).
template <bool EDGE_SCALE>
__global__ __launch_bounds__(256)
void k_agg_wide(const ushortT* __restrict__ hb, const int* __restrict__ cnt,
                const int* __restrict__ bucket, const float* __restrict__ dinv,
                const float* __restrict__ bias, ushortT* __restrict__ outBb,
                float* __restrict__ stats)
{
    const int lane = threadIdx.x & 63;
    const int w    = threadIdx.x >> 6;
    const int sg   = lane >> 4;      // edge slot within group of 4
    const int f    = lane & 15;      // 16B feature octet (features f*8..f*8+7)
    const int wid  = blockIdx.x * 4 + w;
    const int nW   = gridDim.x * 4;
    const uint4* h4 = (const uint4*)hb;   // row = 16 x uint4

    float bl[8];
    #pragma unroll
    for (int i = 0; i < 8; ++i) bl[i] = bias[f * 8 + i];

    float ssum[8], ssq[8];
    #pragma unroll
    for (int i = 0; i < 8; ++i) { ssum[i] = 0.f; ssq[i] = 0.f; }

    for (int n = wid; n < NN; n += nW) {
        int d = cnt[n];
        if (d > BK) d = BK;
        const int* bp = bucket + (size_t)n * BK;
        float a[8];
        #pragma unroll
        for (int i = 0; i < 8; ++i) a[i] = 0.f;

        int j = 0;
        // 16-slot chunks: 4 gathers in flight per lane
        for (; j + 16 <= d; j += 16) {
            int4 pv = *(const int4*)(bp + j + 4 * sg);
            uint4 u0 = h4[(size_t)pv.x * 16 + f];
            uint4 u1 = h4[(size_t)pv.y * 16 + f];
            uint4 u2 = h4[(size_t)pv.z * 16 + f];
            uint4 u3 = h4[(size_t)pv.w * 16 + f];
            if (EDGE_SCALE) {
                float d0 = dinv[pv.x], d1 = dinv[pv.y];
                float d2 = dinv[pv.z], d3 = dinv[pv.w];
                fma8(u0, d0, a);
                fma8(u1, d1, a);
                fma8(u2, d2, a);
                fma8(u3, d3, a);
            } else {
                acc8(u0, a);
                acc8(u1, a);
                acc8(u2, a);
                acc8(u3, a);
            }
        }
        // 8-slot chunks: 2 gathers in flight
        for (; j + 8 <= d; j += 8) {
            int s0 = bp[j + sg];
            int s1 = bp[j + 4 + sg];
            uint4 u0 = h4[(size_t)s0 * 16 + f];
            uint4 u1 = h4[(size_t)s1 * 16 + f];
            if (EDGE_SCALE) {
                float d0 = dinv[s0], d1 = dinv[s1];
                fma8(u0, d0, a);
                fma8(u1, d1, a);
            } else {
                acc8(u0, a);
                acc8(u1, a);
            }
        }
        // tail
        for (; j < d; j += 4) {
            int e = j + sg;
            if (e < d) {
                int s0 = bp[e];
                uint4 u = h4[(size_t)s0 * 16 + f];
                if (EDGE_SCALE) fma8(u, dinv[s0], a);
                else            acc8(u, a);
            }
        }
        #pragma unroll
        for (int i = 0; i < 8; ++i) {
            a[i] += __shfl_xor(a[i], 16);
            a[i] += __shfl_xor(a[i], 32);
        }
        if (lane < 16) {
            uint4 us = h4[(size_t)n * 16 + f];   // self row
            float di = dinv[n];
            if (EDGE_SCALE) fma8(us, di, a);     // self contributes dinv[n]*h[n]
            else            acc8(us, a);
            float v[8];
            #pragma unroll
            for (int i = 0; i < 8; ++i) v[i] = fmaf(di, a[i], bl[i]);
            uint4 o;
            o.x = pack2(v[0], v[1]);
            o.y = pack2(v[2], v[3]);
            o.z = pack2(v[4], v[5]);
            o.w = pack2(v[6], v[7]);
            ((uint4*)(outBb + (size_t)n * DIM))[f] = o;
            #pragma unroll
            for (int i = 0; i < 8; ++i) {
                ssum[i] += v[i];
                ssq[i]  = fmaf(v[i], v[i], ssq[i]);
            }
        }
    }

    __shared__ float ls[4 * 128], lq[4 * 128];
    if (lane < 16) {
        #pragma unroll
        for (int i = 0; i < 8; ++i) {
            ls[w * 128 + f * 8 + i] = ssum[i];
            lq[w * 128 + f * 8 + i] = ssq[i];
        }
    }
    __syncthreads();
    int t = threadIdx.x;
    if (t < 128) {
        float a = ls[t] + ls[128 + t] + ls[256 + t] + ls[384 + t];
        float b = lq[t] + lq[128 + t] + lq[256 + t] + lq[384 + t];
        unsafeAtomicAdd(&stats[t], a);
        unsafeAtomicAdd(&stats[128 + t], b);
    }
}

// ---- MFMA bf16 matmul 128x128, layer 1: BN coef in-kernel, out *= dinv ---
__global__ __launch_bounds__(256)
void k_mm128_l1(const ushortT* __restrict__ inb, const ushortT* __restrict__ WT,
                const float* __restrict__ stats, const float* __restrict__ g,
                const float* __restrict__ be, const float* __restrict__ dinv,
                ushortT* __restrict__ outb)
{
    __shared__ ushortT XS[64 * 136];
    __shared__ float CA[128], CD[128];
    const int tid  = threadIdx.x;
    const int row0 = blockIdx.x * 64;

    if (tid < 128) {
        float mu  = stats[tid] * INVN;
        float var = stats[128 + tid] * INVN - mu * mu;
        float a = g[tid] * rsqrtf(var + BN_EPS);
        CA[tid] = a;
        CD[tid] = be[tid] - mu * a;
    }
    __syncthreads();

    #pragma unroll
    for (int i = 0; i < 4; ++i) {
        int idx = tid + 256 * i;       // uint4 (8 bf16) index: 64 rows x 16
        int r = idx >> 4, c8 = idx & 15;
        int grow = row0 + r;
        uint4 u = {0, 0, 0, 0};
        if (grow < NN) u = ((const uint4*)(inb + (size_t)grow * DIM))[c8];
        float v[8];
        unp8(u, v);
        #pragma unroll
        for (int k = 0; k < 8; ++k)
            v[k] = fmaxf(0.f, fmaf(v[k], CA[c8 * 8 + k], CD[c8 * 8 + k]));
        uint4 o;
        o.x = pack2(v[0], v[1]);
        o.y = pack2(v[2], v[3]);
        o.z = pack2(v[4], v[5]);
        o.w = pack2(v[6], v[7]);
        *(uint4*)(XS + r * 136 + c8 * 8) = o;
    }
    __syncthreads();

    const int w    = tid >> 6;
    const int lane = tid & 63;
    const int q    = lane >> 4;
    const int mr   = lane & 15;
    const int rw   = w * 16;

    floatx4 acc[8];
    #pragma unroll
    for (int t = 0; t < 8; ++t) { acc[t][0] = 0.f; acc[t][1] = 0.f; acc[t][2] = 0.f; acc[t][3] = 0.f; }

    #pragma unroll
    for (int c = 0; c < 4; ++c) {
        short8 a = *(const short8*)(XS + (rw + mr) * 136 + c * 32 + q * 8);
        #pragma unroll
        for (int t = 0; t < 8; ++t) {
            short8 b = *(const short8*)(WT + (size_t)(t * 16 + mr) * 128 + c * 32 + q * 8);
            acc[t] = __builtin_amdgcn_mfma_f32_16x16x32_bf16(a, b, acc[t], 0, 0, 0);
        }
    }

    #pragma unroll
    for (int r = 0; r < 4; ++r) {
        int grow = row0 + rw + q * 4 + r;
        if (grow < NN) {
            float di = dinv[grow];
            #pragma unroll
            for (int t = 0; t < 8; ++t) {
                outb[(size_t)grow * DIM + t * 16 + mr] = f2bf(acc[t][r] * di);
            }
        }
    }
}

// ---- layer-2 matmul 128->10, BN coef in-kernel, bf16 16-col out ----------
// 256 threads / 64 rows per block (was 128/32): same occupancy (LDS-capped
// at 768 thr/CU either way), half the per-block fixed costs.
__global__ __launch_bounds__(256)
void k_mm_l2(const ushortT* __restrict__ inb, const float* __restrict__ W2,
             const float* __restrict__ stats, const float* __restrict__ g,
             const float* __restrict__ be, const float* __restrict__ dinv,
             ushortT* __restrict__ Cb)
{
    __shared__ float WL[128 * 16];   // cols padded 10->16 with zeros
    __shared__ float XS[64 * 128];
    __shared__ float CA[128], CD[128];
    const int tid  = threadIdx.x;
    const int row0 = blockIdx.x * 64;

    if (tid < 128) {
        float mu  = stats[tid] * INVN;
        float var = stats[128 + tid] * INVN - mu * mu;
        float a = g[tid] * rsqrtf(var + BN_EPS);
        CA[tid] = a;
        CD[tid] = be[tid] - mu * a;
    }
    for (int idx = tid; idx < 128 * 16; idx += 256) {
        int k = idx >> 4, c = idx & 15;
        WL[idx] = (c < OC) ? W2[k * OC + c] : 0.0f;
    }
    __syncthreads();

    #pragma unroll
    for (int i = 0; i < 4; ++i) {
        int idx = tid + 256 * i;       // uint4 (8 bf16): 64 rows x 16
        int r = idx >> 4, c8 = idx & 15;
        int grow = row0 + r;
        uint4 u = {0, 0, 0, 0};
        if (grow < NN) u = ((const uint4*)(inb + (size_t)grow * DIM))[c8];
        float v[8];
        unp8(u, v);
        float* xp = XS + r * 128 + c8 * 8;
        #pragma unroll
        for (int k = 0; k < 8; ++k)
            xp[k] = fmaxf(0.f, fmaf(v[k], CA[c8 * 8 + k], CD[c8 * 8 + k]));
    }
    __syncthreads();

    const int cg = tid & 3;
    const int rg = tid >> 2;          // 0..63
    const int grow = row0 + rg;
    float4 acc = {0, 0, 0, 0};
    const float4* XS4 = (const float4*)XS;
    const float4* WL4 = (const float4*)WL;
    for (int k = 0; k < 128; k += 4) {
        float4 w0 = WL4[(k + 0) * 4 + cg];
        float4 w1 = WL4[(k + 1) * 4 + cg];
        float4 w2 = WL4[(k + 2) * 4 + cg];
        float4 w3 = WL4[(k + 3) * 4 + cg];
        float4 x = XS4[rg * 32 + (k >> 2)];
        acc = f4fma(w0, x.x, f4fma(w1, x.y, f4fma(w2, x.z, f4fma(w3, x.w, acc))));
    }
    if (grow < NN) {
        float di = dinv[grow];
        uint2 o;
        o.x = pack2(acc.x * di, acc.y * di);
        o.y = pack2(acc.z * di, acc.w * di);
        ((uint2*)(Cb + (size_t)grow * 16))[cg] = o;   // padded cols are 0
    }
}

// ---- bucket-CSR aggregation, 10 bf16 features: wave = 8 edges x 8 lanes --
// 4-NODE MLP: the per-node chain (bucket load -> dependent 4B gather) is
// latency-bound at deg~16; four independent node chains per wave quadruple
// requests in flight at negligible VGPR cost (accs are scalars).
__global__ __launch_bounds__(256)
void k_agg10(const ushortT* __restrict__ Cb, const int* __restrict__ cnt,
             const int* __restrict__ bucket, const float* __restrict__ dinv,
             const float* __restrict__ b2, float* __restrict__ out)
{
    const int lane = threadIdx.x & 63;
    const int sg   = lane >> 3;      // edge slot 0..7
    const int f    = lane & 7;       // feature pair (cols 2f, 2f+1)
    const int wid  = (blockIdx.x * 256 + threadIdx.x) >> 6;
    const int nW   = gridDim.x * 4;
    const uintT* Cu = (const uintT*)Cb;   // row = 8 uints

    for (int n0 = wid * 4; n0 < NN; n0 += nW * 4) {
        // NN%4==0 and n0%4==0 -> n0+3 < NN; cnt+n0 is 16B aligned
        int4 dd = *(const int4*)(cnt + n0);
        int d0 = dd.x > BK ? BK : dd.x;
        int d1 = dd.y > BK ? BK : dd.y;
        int d2 = dd.z > BK ? BK : dd.z;
        int d3 = dd.w > BK ? BK : dd.w;
        const int* bp0 = bucket + (size_t)(n0 + 0) * BK;
        const int* bp1 = bucket + (size_t)(n0 + 1) * BK;
        const int* bp2 = bucket + (size_t)(n0 + 2) * BK;
        const int* bp3 = bucket + (size_t)(n0 + 3) * BK;
        float a00 = 0.f, a01 = 0.f, a10 = 0.f, a11 = 0.f;
        float a20 = 0.f, a21 = 0.f, a30 = 0.f, a31 = 0.f;
        int dm = d0 > d1 ? d0 : d1;
        if (d2 > dm) dm = d2;
        if (d3 > dm) dm = d3;
        for (int j = sg; j < dm; j += 8) {
            if (j < d0) {
                uintT u = Cu[(size_t)bp0[j] * 8 + f];
                a00 += __uint_as_float(u << 16);
                a01 += __uint_as_float(u & 0xFFFF0000u);
            }
            if (j < d1) {
                uintT u = Cu[(size_t)bp1[j] * 8 + f];
                a10 += __uint_as_float(u << 16);
                a11 += __uint_as_float(u & 0xFFFF0000u);
            }
            if (j < d2) {
                uintT u = Cu[(size_t)bp2[j] * 8 + f];
                a20 += __uint_as_float(u << 16);
                a21 += __uint_as_float(u & 0xFFFF0000u);
            }
            if (j < d3) {
                uintT u = Cu[(size_t)bp3[j] * 8 + f];
                a30 += __uint_as_float(u << 16);
                a31 += __uint_as_float(u & 0xFFFF0000u);
            }
        }
        #pragma unroll
        for (int m = 8; m <= 32; m <<= 1) {
            a00 += __shfl_xor(a00, m); a01 += __shfl_xor(a01, m);
            a10 += __shfl_xor(a10, m); a11 += __shfl_xor(a11, m);
            a20 += __shfl_xor(a20, m); a21 += __shfl_xor(a21, m);
            a30 += __shfl_xor(a30, m); a31 += __shfl_xor(a31, m);
        }
        if (lane < 8) {
            uintT u0 = Cu[(size_t)(n0 + 0) * 8 + f];   // self rows
            uintT u1 = Cu[(size_t)(n0 + 1) * 8 + f];
            uintT u2 = Cu[(size_t)(n0 + 2) * 8 + f];
            uintT u3 = Cu[(size_t)(n0 + 3) * 8 + f];
            a00 += __uint_as_float(u0 << 16); a01 += __uint_as_float(u0 & 0xFFFF0000u);
            a10 += __uint_as_float(u1 << 16); a11 += __uint_as_float(u1 & 0xFFFF0000u);
            a20 += __uint_as_float(u2 << 16); a21 += __uint_as_float(u2 & 0xFFFF0000u);
            a30 += __uint_as_float(u3 << 16); a31 += __uint_as_float(u3 & 0xFFFF0000u);
            float4 dv4 = *(const float4*)(dinv + n0);  // dinv 16B aligned at n0
            if (2 * f < OC) {
                float b2lo = b2[2 * f], b2hi = b2[2 * f + 1];
                float2 o0, o1, o2, o3;
                o0.x = fmaf(dv4.x, a00, b2lo); o0.y = fmaf(dv4.x, a01, b2hi);
                o1.x = fmaf(dv4.y, a10, b2lo); o1.y = fmaf(dv4.y, a11, b2hi);
                o2.x = fmaf(dv4.z, a20, b2lo); o2.y = fmaf(dv4.z, a21, b2hi);
                o3.x = fmaf(dv4.w, a30, b2lo); o3.y = fmaf(dv4.w, a31, b2hi);
                *(float2*)(out + (size_t)(n0 + 0) * OC + 2 * f) = o0;
                *(float2*)(out + (size_t)(n0 + 1) * OC + 2 * f) = o1;
                *(float2*)(out + (size_t)(n0 + 2) * OC + 2 * f) = o2;
                *(float2*)(out + (size_t)(n0 + 3) * OC + 2 * f) = o3;
            }
        }
    }
}

extern "C" void kernel_launch(void* const* d_in, const int* in_sizes, int n_in,
                              void* d_out, int out_size, void* d_ws, size_t ws_size,
                              hipStream_t stream) {
    const float* x    = (const float*)d_in[0];
    const int*   ei   = (const int*)d_in[1];
    const int*   srcv = ei;          // row 0
    const int*   dstv = ei + NE;     // row 1
    const float* W0  = (const float*)d_in[2];
    const float* b0  = (const float*)d_in[3];
    const float* g0  = (const float*)d_in[4];
    const float* be0 = (const float*)d_in[5];
    const float* W1  = (const float*)d_in[6];
    const float* b1  = (const float*)d_in[7];
    const float* g1  = (const float*)d_in[8];
    const float* be1 = (const float*)d_in[9];
    const float* W2  = (const float*)d_in[10];
    const float* b2  = (const float*)d_in[11];
    float* out = (float*)d_out;

    // workspace layout (4-byte words), ~77.7 MB total
    float* base   = (float*)d_ws;
    int*   cnt    = (int*)base;                    // NN (true degree)
    float* dinv   = base + NN;                     // NN
    float* stats  = base + 2 * NN;                 // 512 (L0: +0, L1: +256)
    int*   gcur   = (int*)(stats + 512);           // 512 (BINS used, zeroed by k_wt)
    ushortT* WT0  = (ushortT*)(base + 2 * NN + 1024);      // 8192 words
    ushortT* WT1  = (ushortT*)(base + 2 * NN + 9216);      // 8192 words
    int*   bucket = (int*)(base + 2 * NN + 17408);         // NN*BK ints (64B-aligned)
    ushortT* A_bf = (ushortT*)(base + 2 * NN + 17408 + (size_t)NN * BK);  // NN*64 words
    ushortT* B_bf = A_bf + (size_t)NN * DIM;               // NN*128 bf16
    ushortT* Cb   = A_bf;                          // layer-2 h2' bf16 (aliases A_bf)
    uint2* gbin   = (uint2*)B_bf;                  // 196*16320*8B <= B_bf, freed before agg0

    // weight transposes + stats/gcur zero (independent of graph)
    k_wt<<<128, 256, 0, stream>>>(W0, W1, WT0, WT1, stats);

    // fused: edge binning (782 blocks) + layer-0 matmul (3125 blocks)
    k_p1<<<P1B + 3125, 256, 0, stream>>>(srcv, dstv, gbin, gcur, x, WT0, A_bf);
    // per-bin bucket build + cnt + dinv
    k_p2<<<BINS, 512, 0, stream>>>(gbin, gcur, bucket, cnt, dinv);

    // ---- layer 0: h unscaled -> per-edge dinv[src] scaling in agg ----
    k_agg_wide<true><<<2048, 256, 0, stream>>>(A_bf, cnt, bucket, dinv, b0, B_bf, stats);

    // ---- layer 1 (BN coef from stats computed in-kernel; out pre-scaled) ----
    k_mm128_l1<<<(NN + 63) / 64, 256, 0, stream>>>(B_bf, WT1, stats, g0, be0, dinv, A_bf);
    k_agg_wide<false><<<2048, 256, 0, stream>>>(A_bf, cnt, bucket, dinv, b1, B_bf, stats + 256);

    // ---- layer 2: project to 10 dims first, aggregate cheap ----
    k_mm_l2<<<(NN + 63) / 64, 256, 0, stream>>>(B_bf, W2, stats + 256, g1, be1, dinv, Cb);
    k_agg10<<<1024, 256, 0, stream>>>(Cb, cnt, bucket, dinv, b2, out);
}